// Round 2
// baseline (583.836 us; speedup 1.0000x reference)
//
#include <hip/hip_runtime.h>

// TATWindowAttention: B=16, n=100, L=64, C=256, H=8, Dh=32
// out = concat(x [B,n,L,C], attn [B,n,H,L,L]) fp32.
// One block per (bw, h): 12800 blocks x 256 threads (4 waves).
// MFMA 16x16x32 bf16; split-bf16 (hi+lo) Q,K for precision; bf16 P,V for PV.
// v3: v2 design (direct global->reg Q/K, single barrier, 13.8 KB LDS) but
//     launch_bounds(256,5) -- (256,6) forced a ~84-VGPR cap -> spill risk.

typedef __attribute__((ext_vector_type(8))) short bf16x8;
typedef __attribute__((ext_vector_type(4))) float f32x4;

#define LOGIT_MAX_F 4.605170185988091f  // log(100)

__device__ __forceinline__ short f2bf(float f) {
    union { float f; unsigned u; } c; c.f = f;
    unsigned r = c.u + 0x7FFFu + ((c.u >> 16) & 1u);
    return (short)(r >> 16);
}
__device__ __forceinline__ float bf2f(short s) {
    union { unsigned u; float f; } c; c.u = ((unsigned)(unsigned short)s) << 16;
    return c.f;
}

// LDS layout (shorts): VT[32*72] @0 (V transposed: VT[d][k]); P[64*72] @2304.
#define VT_OFF 0
#define P_OFF  (32 * 72)
#define SMEM_SHORTS (32 * 72 + 64 * 72)   // 6912 shorts = 13824 B

// Convert one K row-chunk (8 fp32) to split bf16 and run the 3 precision MFMAs.
__device__ __forceinline__ f32x4 qk_tile(const float4 ka, const float4 kb2,
                                         const bf16x8 qh, const bf16x8 ql,
                                         f32x4 acc)
{
    const float kf[8] = {ka.x, ka.y, ka.z, ka.w, kb2.x, kb2.y, kb2.z, kb2.w};
    bf16x8 kh, kl;
    #pragma unroll
    for (int i = 0; i < 8; ++i) {
        const short hi = f2bf(kf[i]);
        kh[i] = hi;
        kl[i] = f2bf(kf[i] - bf2f(hi));
    }
    acc = __builtin_amdgcn_mfma_f32_16x16x32_bf16(qh, kh, acc, 0, 0, 0);
    acc = __builtin_amdgcn_mfma_f32_16x16x32_bf16(qh, kl, acc, 0, 0, 0);
    acc = __builtin_amdgcn_mfma_f32_16x16x32_bf16(ql, kh, acc, 0, 0, 0);
    return acc;
}

__global__ __launch_bounds__(256, 5) void tat_attn_kernel(
    const float* __restrict__ Qg, const float* __restrict__ Kg,
    const float* __restrict__ Vg, const float* __restrict__ Pg,
    const float* __restrict__ LSg,
    float* __restrict__ Xout, float* __restrict__ Aout)
{
    constexpr int L = 64, C = 256, H = 8, NW = 100;
    __shared__ short smem[SMEM_SHORTS];

    const int blk = blockIdx.x;
    const int h  = blk & 7;
    const int bw = blk >> 3;
    const int t  = threadIdx.x;
    const int wave = t >> 6;
    const int lane = t & 63;
    const int quad = lane >> 4;
    const int l15  = lane & 15;

    const float* qb = Qg + (size_t)bw * L * C + h * 32;
    const float* kb = Kg + (size_t)bw * L * C + h * 32;
    const float* vb = Vg + (size_t)bw * L * C + h * 32;
    const int b = bw / NW;
    const float* pb = Pg + (size_t)(b * H + h) * L * L;
    float* xb = Xout + (size_t)bw * L * C + h * 32;
    float* ab = Aout + ((size_t)bw * H + h) * L * L;

    const float scale = __expf(fminf(LSg[h], LOGIT_MAX_F));

    // ---- Issue first load batch: V (for LDS), Q frag, K tiles 0,1 ----
    const float4 v0 = *(const float4*)(vb + lane * C + wave * 8);
    const float4 v1 = *(const float4*)(vb + lane * C + wave * 8 + 4);
    const int qrow = 16 * wave + l15;
    const float4 q0 = *(const float4*)(qb + qrow * C + quad * 8);
    const float4 q1 = *(const float4*)(qb + qrow * C + quad * 8 + 4);
    const float4 k0a = *(const float4*)(kb + l15 * C + quad * 8);
    const float4 k0b = *(const float4*)(kb + l15 * C + quad * 8 + 4);
    const float4 k1a = *(const float4*)(kb + (16 + l15) * C + quad * 8);
    const float4 k1b = *(const float4*)(kb + (16 + l15) * C + quad * 8 + 4);

    // ---- V -> LDS transposed bf16: VT[d][k], wave w owns d = 8w..8w+7 ----
    {
        const float va[8] = {v0.x, v0.y, v0.z, v0.w, v1.x, v1.y, v1.z, v1.w};
        #pragma unroll
        for (int i = 0; i < 8; ++i)
            smem[VT_OFF + (wave * 8 + i) * 72 + lane] = f2bf(va[i]);
    }

    // ---- Q -> split bf16 fragment (A-frag: row 16w+l15, k = quad*8+i) ----
    bf16x8 qh, ql;
    {
        const float qa[8] = {q0.x, q0.y, q0.z, q0.w, q1.x, q1.y, q1.z, q1.w};
        #pragma unroll
        for (int i = 0; i < 8; ++i) {
            const short hi = f2bf(qa[i]);
            qh[i] = hi;
            ql[i] = f2bf(qa[i] - bf2f(hi));
        }
    }

    // ---- Issue K tiles 2,3 while tiles 0,1 compute ----
    const float4 k2a = *(const float4*)(kb + (32 + l15) * C + quad * 8);
    const float4 k2b = *(const float4*)(kb + (32 + l15) * C + quad * 8 + 4);
    const float4 k3a = *(const float4*)(kb + (48 + l15) * C + quad * 8);
    const float4 k3b = *(const float4*)(kb + (48 + l15) * C + quad * 8 + 4);

    // ---- QK^T: wave w owns q-rows 16w..16w+15; S block 16x64 = 4 tiles ----
    f32x4 acc0 = {0,0,0,0}, acc1 = {0,0,0,0}, acc2 = {0,0,0,0}, acc3 = {0,0,0,0};
    acc0 = qk_tile(k0a, k0b, qh, ql, acc0);
    acc1 = qk_tile(k1a, k1b, qh, ql, acc1);
    acc2 = qk_tile(k2a, k2b, qh, ql, acc2);
    acc3 = qk_tile(k3a, k3b, qh, ql, acc3);

    // ---- logits = acc*scale + pos; C/D layout: row=quad*4+r (+16w), col=l15+16*t4 ----
    float lg[4][4];
    #pragma unroll
    for (int r = 0; r < 4; ++r) {
        const int row = 16 * wave + quad * 4 + r;
        const int cb  = row * L + l15;
        lg[0][r] = fmaf(acc0[r], scale, pb[cb + 0]);
        lg[1][r] = fmaf(acc1[r], scale, pb[cb + 16]);
        lg[2][r] = fmaf(acc2[r], scale, pb[cb + 32]);
        lg[3][r] = fmaf(acc3[r], scale, pb[cb + 48]);
    }

    // ---- softmax per row: 4 tiles in regs x 16 lanes (xor shuffles) ----
    float p[4][4];
    #pragma unroll
    for (int r = 0; r < 4; ++r) {
        float m = fmaxf(fmaxf(lg[0][r], lg[1][r]), fmaxf(lg[2][r], lg[3][r]));
        #pragma unroll
        for (int off = 8; off > 0; off >>= 1) m = fmaxf(m, __shfl_xor(m, off));
        const float e0 = __expf(lg[0][r] - m);
        const float e1 = __expf(lg[1][r] - m);
        const float e2 = __expf(lg[2][r] - m);
        const float e3 = __expf(lg[3][r] - m);
        float s = (e0 + e1) + (e2 + e3);
        #pragma unroll
        for (int off = 8; off > 0; off >>= 1) s += __shfl_xor(s, off);
        const float inv = 1.0f / s;
        p[0][r] = e0 * inv; p[1][r] = e1 * inv; p[2][r] = e2 * inv; p[3][r] = e3 * inv;
    }

    // ---- attn out (fp32 exact) + P -> LDS (bf16, own-wave rows only) ----
    #pragma unroll
    for (int r = 0; r < 4; ++r) {
        const int row = 16 * wave + quad * 4 + r;
        #pragma unroll
        for (int t4 = 0; t4 < 4; ++t4) {
            const int col = 16 * t4 + l15;
            ab[row * L + col] = p[t4][r];
            smem[P_OFF + row * 72 + col] = f2bf(p[t4][r]);
        }
    }

    // single barrier: makes all waves' VT writes visible (P rows are same-wave)
    __syncthreads();

    // ---- PV: O[16x32] per wave = P[16x64] x V[64x32] ----
    f32x4 o0 = {0,0,0,0}, o1 = {0,0,0,0};
    #pragma unroll
    for (int hh = 0; hh < 2; ++hh) {
        const bf16x8 ap  = *(const bf16x8*)(smem + P_OFF + (16 * wave + l15) * 72 + hh * 32 + quad * 8);
        const bf16x8 bv0 = *(const bf16x8*)(smem + VT_OFF + l15 * 72        + hh * 32 + quad * 8);
        const bf16x8 bv1 = *(const bf16x8*)(smem + VT_OFF + (l15 + 16) * 72 + hh * 32 + quad * 8);
        o0 = __builtin_amdgcn_mfma_f32_16x16x32_bf16(ap, bv0, o0, 0, 0, 0);
        o1 = __builtin_amdgcn_mfma_f32_16x16x32_bf16(ap, bv1, o1, 0, 0, 0);
    }

    #pragma unroll
    for (int r = 0; r < 4; ++r) {
        const int row = 16 * wave + quad * 4 + r;
        xb[row * C + l15]      = o0[r];
        xb[row * C + 16 + l15] = o1[r];
    }
}

extern "C" void kernel_launch(void* const* d_in, const int* in_sizes, int n_in,
                              void* d_out, int out_size, void* d_ws, size_t ws_size,
                              hipStream_t stream) {
    const float* q   = (const float*)d_in[0];
    const float* k   = (const float*)d_in[1];
    const float* v   = (const float*)d_in[2];
    const float* pos = (const float*)d_in[3];
    const float* ls  = (const float*)d_in[4];
    float* out = (float*)d_out;

    constexpr int B = 16, NW = 100, L = 64, C = 256, H = 8;
    float* x_out = out;
    float* a_out = out + (size_t)B * NW * L * C;

    const int blocks = B * NW * H;   // 12800
    tat_attn_kernel<<<blocks, 256, 0, stream>>>(q, k, v, pos, ls, x_out, a_out);
}

// Round 3
// 545.056 us; speedup vs baseline: 1.0711x; 1.0711x over previous
//
#include <hip/hip_runtime.h>

// TATWindowAttention: B=16, n=100, L=64, C=256, H=8, Dh=32
// out = concat(x [B,n,L,C], attn [B,n,H,L,L]) fp32.
// One block per (bw, h): 12800 blocks x 256 threads (4 waves).
// MFMA 16x16x32 bf16; split-bf16 (hi+lo) Q,K for precision; bf16 P,V for PV.
// v4: K,V staged cooperatively in LDS (TLP hides load latency -- v3's
//     direct-to-reg K serialized at VGPR=36). Q direct-to-reg (own-wave only).
//     P region does NOT alias K -> single barrier. pos prefetched pre-barrier.

typedef __attribute__((ext_vector_type(8))) short bf16x8;
typedef __attribute__((ext_vector_type(4))) float f32x4;

#define LOGIT_MAX_F 4.605170185988091f  // log(100)

__device__ __forceinline__ short f2bf(float f) {
    union { float f; unsigned u; } c; c.f = f;
    unsigned r = c.u + 0x7FFFu + ((c.u >> 16) & 1u);
    return (short)(r >> 16);
}
__device__ __forceinline__ float bf2f(short s) {
    union { unsigned u; float f; } c; c.u = ((unsigned)(unsigned short)s) << 16;
    return c.f;
}

// LDS layout (shorts): KHI[64*40] @0, KLO @2560, VT[32*72] @5120 (V^T: VT[d][k]),
// P[64*72] @7424.  No aliasing -> single barrier.
#define KHI_OFF 0
#define KLO_OFF 2560
#define VT_OFF  5120
#define P_OFF   7424
#define SMEM_SHORTS 12032   // 24064 B -> 5 blocks/CU at launch_bounds(256,5)

__global__ __launch_bounds__(256, 5) void tat_attn_kernel(
    const float* __restrict__ Qg, const float* __restrict__ Kg,
    const float* __restrict__ Vg, const float* __restrict__ Pg,
    const float* __restrict__ LSg,
    float* __restrict__ Xout, float* __restrict__ Aout)
{
    constexpr int L = 64, C = 256, H = 8, NW = 100;
    __shared__ short smem[SMEM_SHORTS];

    const int blk = blockIdx.x;
    const int h  = blk & 7;
    const int bw = blk >> 3;
    const int t  = threadIdx.x;
    const int wave = t >> 6;
    const int lane = t & 63;
    const int quad = lane >> 4;
    const int l15  = lane & 15;

    const float* qb = Qg + (size_t)bw * L * C + h * 32;
    const float* kb = Kg + (size_t)bw * L * C + h * 32;
    const float* vb = Vg + (size_t)bw * L * C + h * 32;
    const int b = bw / NW;
    const float* pb = Pg + (size_t)(b * H + h) * L * L;
    float* xb = Xout + (size_t)bw * L * C + h * 32;
    float* ab = Aout + ((size_t)bw * H + h) * L * L;

    const float scale = __expf(fminf(LSg[h], LOGIT_MAX_F));

    // ---- Issue staging loads: K (coop rows), V (strided), Q (own frag) ----
    const int r8 = t >> 2;            // K row 0..63
    const int c8 = (t & 3) * 8;       // K col base 0,8,16,24
    const float4 k0 = *(const float4*)(kb + r8 * C + c8);
    const float4 k1 = *(const float4*)(kb + r8 * C + c8 + 4);

    const float4 v0 = *(const float4*)(vb + lane * C + wave * 8);
    const float4 v1 = *(const float4*)(vb + lane * C + wave * 8 + 4);

    const int qrow = 16 * wave + l15;
    const float4 q0 = *(const float4*)(qb + qrow * C + quad * 8);
    const float4 q1 = *(const float4*)(qb + qrow * C + quad * 8 + 4);

    // ---- Prefetch position (L2-resident; latency hides under staging+QK) ----
    float posr[4][4];
    #pragma unroll
    for (int r = 0; r < 4; ++r) {
        const int cb = (16 * wave + quad * 4 + r) * L + l15;
        posr[0][r] = pb[cb + 0];
        posr[1][r] = pb[cb + 16];
        posr[2][r] = pb[cb + 32];
        posr[3][r] = pb[cb + 48];
    }

    // ---- K -> split bf16 -> LDS [64][40] ----
    {
        const float ka[8] = {k0.x,k0.y,k0.z,k0.w,k1.x,k1.y,k1.z,k1.w};
        bf16x8 kh, kl;
        #pragma unroll
        for (int i = 0; i < 8; ++i) {
            const short hi = f2bf(ka[i]);
            kh[i] = hi;
            kl[i] = f2bf(ka[i] - bf2f(hi));
        }
        *(bf16x8*)(smem + KHI_OFF + r8 * 40 + c8) = kh;
        *(bf16x8*)(smem + KLO_OFF + r8 * 40 + c8) = kl;
    }

    // ---- V -> LDS transposed bf16: VT[d][k], wave w owns d = 8w..8w+7 ----
    {
        const float va[8] = {v0.x,v0.y,v0.z,v0.w,v1.x,v1.y,v1.z,v1.w};
        #pragma unroll
        for (int i = 0; i < 8; ++i)
            smem[VT_OFF + (wave * 8 + i) * 72 + lane] = f2bf(va[i]);
    }

    // ---- Q -> split bf16 fragment in regs (A-frag: row 16w+l15, k=quad*8+i) ----
    bf16x8 qh, ql;
    {
        const float qa[8] = {q0.x,q0.y,q0.z,q0.w,q1.x,q1.y,q1.z,q1.w};
        #pragma unroll
        for (int i = 0; i < 8; ++i) {
            const short hi = f2bf(qa[i]);
            qh[i] = hi;
            ql[i] = f2bf(qa[i] - bf2f(hi));
        }
    }

    __syncthreads();   // the ONLY barrier: K/VT visible to all waves

    // ---- QK^T: wave w owns q-rows 16w..16w+15; S block 16x64 = 4 tiles ----
    f32x4 acc0 = {0,0,0,0}, acc1 = {0,0,0,0}, acc2 = {0,0,0,0}, acc3 = {0,0,0,0};
    #pragma unroll
    for (int t4 = 0; t4 < 4; ++t4) {
        const bf16x8 bkh = *(const bf16x8*)(smem + KHI_OFF + (16*t4 + l15)*40 + quad*8);
        const bf16x8 bkl = *(const bf16x8*)(smem + KLO_OFF + (16*t4 + l15)*40 + quad*8);
        f32x4 a = (t4==0)?acc0:(t4==1)?acc1:(t4==2)?acc2:acc3;
        a = __builtin_amdgcn_mfma_f32_16x16x32_bf16(qh, bkh, a, 0, 0, 0);
        a = __builtin_amdgcn_mfma_f32_16x16x32_bf16(qh, bkl, a, 0, 0, 0);
        a = __builtin_amdgcn_mfma_f32_16x16x32_bf16(ql, bkh, a, 0, 0, 0);
        if (t4==0) acc0 = a; else if (t4==1) acc1 = a; else if (t4==2) acc2 = a; else acc3 = a;
    }

    // ---- logits = acc*scale + pos; C/D layout: row=quad*4+r (+16w), col=l15+16*t4 ----
    float lg[4][4];
    #pragma unroll
    for (int r = 0; r < 4; ++r) {
        lg[0][r] = fmaf(acc0[r], scale, posr[0][r]);
        lg[1][r] = fmaf(acc1[r], scale, posr[1][r]);
        lg[2][r] = fmaf(acc2[r], scale, posr[2][r]);
        lg[3][r] = fmaf(acc3[r], scale, posr[3][r]);
    }

    // ---- softmax per row: 4 tiles in regs x 16 lanes (xor shuffles) ----
    float p[4][4];
    #pragma unroll
    for (int r = 0; r < 4; ++r) {
        float m = fmaxf(fmaxf(lg[0][r], lg[1][r]), fmaxf(lg[2][r], lg[3][r]));
        #pragma unroll
        for (int off = 8; off > 0; off >>= 1) m = fmaxf(m, __shfl_xor(m, off));
        const float e0 = __expf(lg[0][r] - m);
        const float e1 = __expf(lg[1][r] - m);
        const float e2 = __expf(lg[2][r] - m);
        const float e3 = __expf(lg[3][r] - m);
        float s = (e0 + e1) + (e2 + e3);
        #pragma unroll
        for (int off = 8; off > 0; off >>= 1) s += __shfl_xor(s, off);
        const float inv = 1.0f / s;
        p[0][r] = e0 * inv; p[1][r] = e1 * inv; p[2][r] = e2 * inv; p[3][r] = e3 * inv;
    }

    // ---- attn out (fp32 exact) + P -> LDS (bf16; own-wave rows, no alias) ----
    #pragma unroll
    for (int r = 0; r < 4; ++r) {
        const int row = 16 * wave + quad * 4 + r;
        #pragma unroll
        for (int t4 = 0; t4 < 4; ++t4) {
            const int col = 16 * t4 + l15;
            ab[row * L + col] = p[t4][r];
            smem[P_OFF + row * 72 + col] = f2bf(p[t4][r]);
        }
    }

    // ---- PV: O[16x32] per wave = P[16x64] x V[64x32] (P same-wave, VT pre-barrier) ----
    f32x4 o0 = {0,0,0,0}, o1 = {0,0,0,0};
    #pragma unroll
    for (int hh = 0; hh < 2; ++hh) {
        const bf16x8 ap  = *(const bf16x8*)(smem + P_OFF + (16*wave + l15)*72 + hh*32 + quad*8);
        const bf16x8 bv0 = *(const bf16x8*)(smem + VT_OFF + l15*72        + hh*32 + quad*8);
        const bf16x8 bv1 = *(const bf16x8*)(smem + VT_OFF + (l15+16)*72   + hh*32 + quad*8);
        o0 = __builtin_amdgcn_mfma_f32_16x16x32_bf16(ap, bv0, o0, 0, 0, 0);
        o1 = __builtin_amdgcn_mfma_f32_16x16x32_bf16(ap, bv1, o1, 0, 0, 0);
    }

    #pragma unroll
    for (int r = 0; r < 4; ++r) {
        const int row = 16 * wave + quad * 4 + r;
        xb[row * C + l15]      = o0[r];
        xb[row * C + 16 + l15] = o1[r];
    }
}

extern "C" void kernel_launch(void* const* d_in, const int* in_sizes, int n_in,
                              void* d_out, int out_size, void* d_ws, size_t ws_size,
                              hipStream_t stream) {
    const float* q   = (const float*)d_in[0];
    const float* k   = (const float*)d_in[1];
    const float* v   = (const float*)d_in[2];
    const float* pos = (const float*)d_in[3];
    const float* ls  = (const float*)d_in[4];
    float* out = (float*)d_out;

    constexpr int B = 16, NW = 100, L = 64, C = 256, H = 8;
    float* x_out = out;
    float* a_out = out + (size_t)B * NW * L * C;

    const int blocks = B * NW * H;   // 12800
    tat_attn_kernel<<<blocks, 256, 0, stream>>>(q, k, v, pos, ls, x_out, a_out);
}